// Round 4
// baseline (368.829 us; speedup 1.0000x reference)
//
#include <hip/hip_runtime.h>
#include <cstdint>
#include <cstddef>

#define T 4096
#define C 768
#define HD 64
#define NH 12

typedef float f32x4 __attribute__((ext_vector_type(4)));
typedef float f32x16 __attribute__((ext_vector_type(16)));
typedef __bf16 bf16x8 __attribute__((ext_vector_type(8)));
typedef unsigned short u16;

static __device__ __forceinline__ u16 f2bf(float f) {
    union { __bf16 h; u16 u; } cv;
    cv.h = (__bf16)f;
    return cv.u;
}

static __device__ __forceinline__ float exp2_hw(float x) {
    float r;
    asm("v_exp_f32 %0, %1" : "=v"(r) : "v"(x));
    return r;
}

static __device__ __forceinline__ void load_lds16(const void* g, void* l) {
    __builtin_amdgcn_global_load_lds(
        (const __attribute__((address_space(1))) void*)g,
        (__attribute__((address_space(3))) void*)l, 16, 0, 0);
}

// ---------------------------------------------------------------- converts
__global__ __launch_bounds__(256) void cvt_main(
    const float* __restrict__ hs, const float* __restrict__ w0,
    const float* __restrict__ w1, const float* __restrict__ w2,
    const float* __restrict__ w3,
    u16* __restrict__ dhs, u16* __restrict__ dw0, u16* __restrict__ dw1,
    u16* __restrict__ dw2, u16* __restrict__ dw3) {
    const int NHS = T * C;
    const int NW = C * C;
    int i = (blockIdx.x * 256 + threadIdx.x) * 4;
    const float* s; u16* d; int j;
    if (i < NHS) { s = hs; d = dhs; j = i; }
    else {
        j = i - NHS;
        int t = j / NW; j -= t * NW;
        s = (t == 0) ? w0 : (t == 1) ? w1 : (t == 2) ? w2 : w3;
        d = (t == 0) ? dw0 : (t == 1) ? dw1 : (t == 2) ? dw2 : dw3;
    }
    float4 v = *(const float4*)(s + j);
    d[j + 0] = f2bf(v.x);
    d[j + 1] = f2bf(v.y);
    d[j + 2] = f2bf(v.z);
    d[j + 3] = f2bf(v.w);
}

__global__ __launch_bounds__(256) void cvt_rel(const float* __restrict__ rh,
                                               const float* __restrict__ rw,
                                               u16* __restrict__ drh,
                                               u16* __restrict__ drw) {
    const int N = 127 * HD;
    int i = (blockIdx.x * 256 + threadIdx.x) * 4;
    if (i >= 2 * N) return;
    const float* s = (i < N) ? rh : rw;
    u16* d = (i < N) ? drh : drw;
    int j = (i < N) ? i : i - N;
    float4 v = *(const float4*)(s + j);
    d[j + 0] = f2bf(v.x);
    d[j + 1] = f2bf(v.y);
    d[j + 2] = f2bf(v.z);
    d[j + 3] = f2bf(v.w);
}

// ---------------------------------------------------------------- QKV GEMM
__global__ __launch_bounds__(256, 2) void gemm_qkv_kernel(
    const u16* __restrict__ xb,
    const u16* __restrict__ wq, const u16* __restrict__ wk, const u16* __restrict__ wv,
    const float* __restrict__ qb, const float* __restrict__ kb, const float* __restrict__ vb,
    u16* __restrict__ Q, u16* __restrict__ K, u16* __restrict__ V) {
    __shared__ __align__(16) u16 As[128 * 32];
    __shared__ __align__(16) u16 Bs[128 * 32];
    const int z = blockIdx.z;
    const u16* W = (z == 0) ? wq : (z == 1) ? wk : wv;
    const float* bias = (z == 0) ? qb : (z == 1) ? kb : vb;
    u16* dst = (z == 0) ? Q : (z == 1) ? K : V;
    const int m0 = blockIdx.x * 128, n0 = blockIdx.y * 128;
    const int tid = threadIdx.x;
    const int wave = tid >> 6, lane = tid & 63, quad = lane >> 4, l15 = lane & 15;
    const int r0 = (wave >> 1) * 64, c0 = (wave & 1) * 64;
    f32x4 acc[4][4] = {};
    float4 av[2], bv[2];
#pragma unroll
    for (int i = 0; i < 2; ++i) {
        int c = i * 256 + tid;
        int row = c >> 2, col = (c & 3) * 8;
        av[i] = *(const float4*)(xb + (size_t)(m0 + row) * C + col);
        bv[i] = *(const float4*)(W + (size_t)(n0 + row) * C + col);
    }
    for (int k0 = 0; k0 < C; k0 += 32) {
        __syncthreads();
#pragma unroll
        for (int i = 0; i < 2; ++i) {
            int c = i * 256 + tid;
            int row = c >> 2, col = (c & 3) * 8;
            *(float4*)&As[row * 32 + col] = av[i];
            *(float4*)&Bs[row * 32 + col] = bv[i];
        }
        __syncthreads();
        if (k0 + 32 < C) {
#pragma unroll
            for (int i = 0; i < 2; ++i) {
                int c = i * 256 + tid;
                int row = c >> 2, col = (c & 3) * 8;
                av[i] = *(const float4*)(xb + (size_t)(m0 + row) * C + k0 + 32 + col);
                bv[i] = *(const float4*)(W + (size_t)(n0 + row) * C + k0 + 32 + col);
            }
        }
        bf16x8 af[4], bfr[4];
#pragma unroll
        for (int mi = 0; mi < 4; ++mi)
            af[mi] = *(const bf16x8*)&As[(r0 + mi * 16 + l15) * 32 + quad * 8];
#pragma unroll
        for (int ni = 0; ni < 4; ++ni)
            bfr[ni] = *(const bf16x8*)&Bs[(c0 + ni * 16 + l15) * 32 + quad * 8];
#pragma unroll
        for (int mi = 0; mi < 4; ++mi)
#pragma unroll
            for (int ni = 0; ni < 4; ++ni)
                acc[mi][ni] = __builtin_amdgcn_mfma_f32_16x16x32_bf16(af[mi], bfr[ni], acc[mi][ni], 0, 0, 0);
    }
#pragma unroll
    for (int mi = 0; mi < 4; ++mi)
#pragma unroll
        for (int ni = 0; ni < 4; ++ni)
#pragma unroll
            for (int r = 0; r < 4; ++r) {
                int m = m0 + r0 + mi * 16 + quad * 4 + r;
                int n = n0 + c0 + ni * 16 + l15;
                float v = acc[mi][ni][r] + bias[n];
                dst[(size_t)(n >> 6) * T * HD + (size_t)m * HD + (n & 63)] = f2bf(v);
            }
}

// ---------------------------------------------------------------- proj GEMM
__global__ __launch_bounds__(256, 2) void gemm_proj_kernel(
    const u16* __restrict__ A, const u16* __restrict__ W,
    const float* __restrict__ bias, float* __restrict__ out) {
    __shared__ __align__(16) u16 As[128 * 32];
    __shared__ __align__(16) u16 Bs[128 * 32];
    const int m0 = blockIdx.x * 128, n0 = blockIdx.y * 128;
    const int tid = threadIdx.x;
    const int wave = tid >> 6, lane = tid & 63, quad = lane >> 4, l15 = lane & 15;
    const int r0 = (wave >> 1) * 64, c0 = (wave & 1) * 64;
    f32x4 acc[4][4] = {};
    float4 av[2], bv[2];
#pragma unroll
    for (int i = 0; i < 2; ++i) {
        int c = i * 256 + tid;
        int row = c >> 2, col = (c & 3) * 8;
        av[i] = *(const float4*)(A + (size_t)(m0 + row) * C + col);
        bv[i] = *(const float4*)(W + (size_t)(n0 + row) * C + col);
    }
    for (int k0 = 0; k0 < C; k0 += 32) {
        __syncthreads();
#pragma unroll
        for (int i = 0; i < 2; ++i) {
            int c = i * 256 + tid;
            int row = c >> 2, col = (c & 3) * 8;
            *(float4*)&As[row * 32 + col] = av[i];
            *(float4*)&Bs[row * 32 + col] = bv[i];
        }
        __syncthreads();
        if (k0 + 32 < C) {
#pragma unroll
            for (int i = 0; i < 2; ++i) {
                int c = i * 256 + tid;
                int row = c >> 2, col = (c & 3) * 8;
                av[i] = *(const float4*)(A + (size_t)(m0 + row) * C + k0 + 32 + col);
                bv[i] = *(const float4*)(W + (size_t)(n0 + row) * C + k0 + 32 + col);
            }
        }
        bf16x8 af[4], bfr[4];
#pragma unroll
        for (int mi = 0; mi < 4; ++mi)
            af[mi] = *(const bf16x8*)&As[(r0 + mi * 16 + l15) * 32 + quad * 8];
#pragma unroll
        for (int ni = 0; ni < 4; ++ni)
            bfr[ni] = *(const bf16x8*)&Bs[(c0 + ni * 16 + l15) * 32 + quad * 8];
#pragma unroll
        for (int mi = 0; mi < 4; ++mi)
#pragma unroll
            for (int ni = 0; ni < 4; ++ni)
                acc[mi][ni] = __builtin_amdgcn_mfma_f32_16x16x32_bf16(af[mi], bfr[ni], acc[mi][ni], 0, 0, 0);
    }
#pragma unroll
    for (int mi = 0; mi < 4; ++mi)
#pragma unroll
        for (int ni = 0; ni < 4; ++ni)
#pragma unroll
            for (int r = 0; r < 4; ++r) {
                int m = m0 + r0 + mi * 16 + quad * 4 + r;
                int n = n0 + c0 + ni * 16 + l15;
                out[(size_t)m * C + n] = acc[mi][ni][r] + bias[n];
            }
}

// ---------------------------------------------------------------- V transpose
__global__ __launch_bounds__(256) void vtrans_kernel(const u16* __restrict__ V,
                                                     u16* __restrict__ Vt) {
    __shared__ __align__(16) u16 tl[64 * 72];
    const int h = blockIdx.y, t0 = blockIdx.x * 64, tid = threadIdx.x;
#pragma unroll
    for (int i = 0; i < 2; ++i) {
        int c = i * 256 + tid;
        int row = c >> 3, col = (c & 7) * 8;
        union { float4 f; u16 u[8]; } cv;
        cv.f = *(const float4*)(V + (size_t)h * T * HD + (size_t)(t0 + row) * HD + col);
#pragma unroll
        for (int j = 0; j < 8; ++j) tl[(col + j) * 72 + row] = cv.u[j];
    }
    __syncthreads();
#pragma unroll
    for (int i = 0; i < 2; ++i) {
        int c = i * 256 + tid;
        int drow = c >> 3, tcol = (c & 7) * 8;
        float4 v = *(const float4*)&tl[drow * 72 + tcol];
        *(float4*)(Vt + (size_t)(h * HD + drow) * T + t0 + tcol) = v;
    }
}

// ---------------------------------------------------------------- rel_h
// OUTPUT LAYOUT: relH[h][hq][hk][wq]  (transposed for vectorized attn loads),
// pre-scaled by log2e. Computed as D[hk][wq] = Rh . q^T (A=Rh rows, B=q rows).
__global__ __launch_bounds__(64, 2) void relh_kernel(const u16* __restrict__ Q,
                                                     const u16* __restrict__ rph,
                                                     float* __restrict__ relH) {
    const float LOG2E = 1.4426950408889634f;
    const int hq = blockIdx.x, h = blockIdx.y;
    const int lane = threadIdx.x, quad = lane >> 4, l15 = lane & 15;
    f32x4 acc[4][4] = {};
    bf16x8 a[4][2], b[4][2];
#pragma unroll
    for (int mi = 0; mi < 4; ++mi)
#pragma unroll
        for (int kk = 0; kk < 2; ++kk) {
            int hk = mi * 16 + l15;
            a[mi][kk] = *(const bf16x8*)(rph + (size_t)(hq - hk + 63) * HD + kk * 32 + quad * 8);
        }
#pragma unroll
    for (int ni = 0; ni < 4; ++ni)
#pragma unroll
        for (int kk = 0; kk < 2; ++kk)
            b[ni][kk] = *(const bf16x8*)(Q + (size_t)h * T * HD +
                                         (size_t)(hq * 64 + ni * 16 + l15) * HD + kk * 32 + quad * 8);
#pragma unroll
    for (int mi = 0; mi < 4; ++mi)
#pragma unroll
        for (int ni = 0; ni < 4; ++ni) {
            acc[mi][ni] = __builtin_amdgcn_mfma_f32_16x16x32_bf16(a[mi][0], b[ni][0], acc[mi][ni], 0, 0, 0);
            acc[mi][ni] = __builtin_amdgcn_mfma_f32_16x16x32_bf16(a[mi][1], b[ni][1], acc[mi][ni], 0, 0, 0);
        }
#pragma unroll
    for (int mi = 0; mi < 4; ++mi)
#pragma unroll
        for (int ni = 0; ni < 4; ++ni)
#pragma unroll
            for (int r = 0; r < 4; ++r) {
                int hk = mi * 16 + quad * 4 + r;
                int wq = ni * 16 + l15;
                relH[((size_t)(h * 64 + hq) * 64 + hk) * 64 + wq] = acc[mi][ni][r] * LOG2E;
            }
}

// ---------------------------------------------------------------- rel_w: [h][t][wk], *log2e
__global__ __launch_bounds__(64, 2) void relw_kernel(const u16* __restrict__ Q,
                                                     const u16* __restrict__ rpw,
                                                     float* __restrict__ relW) {
    const float LOG2E = 1.4426950408889634f;
    const int wq = blockIdx.x, mt = blockIdx.y;
    const int lane = threadIdx.x, quad = lane >> 4, l15 = lane & 15;
    f32x4 acc[4][4] = {};
    bf16x8 a[4][2], b[4][2];
#pragma unroll
    for (int mi = 0; mi < 4; ++mi)
#pragma unroll
        for (int kk = 0; kk < 2; ++kk) {
            int fh = mt * 64 + mi * 16 + l15;
            a[mi][kk] = *(const bf16x8*)(Q + (size_t)(fh >> 6) * T * HD +
                                         (size_t)((fh & 63) * 64 + wq) * HD + kk * 32 + quad * 8);
        }
#pragma unroll
    for (int ni = 0; ni < 4; ++ni)
#pragma unroll
        for (int kk = 0; kk < 2; ++kk) {
            int wk = ni * 16 + l15;
            b[ni][kk] = *(const bf16x8*)(rpw + (size_t)(wq - wk + 63) * HD + kk * 32 + quad * 8);
        }
#pragma unroll
    for (int mi = 0; mi < 4; ++mi)
#pragma unroll
        for (int ni = 0; ni < 4; ++ni) {
            acc[mi][ni] = __builtin_amdgcn_mfma_f32_16x16x32_bf16(a[mi][0], b[ni][0], acc[mi][ni], 0, 0, 0);
            acc[mi][ni] = __builtin_amdgcn_mfma_f32_16x16x32_bf16(a[mi][1], b[ni][1], acc[mi][ni], 0, 0, 0);
        }
#pragma unroll
    for (int mi = 0; mi < 4; ++mi)
#pragma unroll
        for (int ni = 0; ni < 4; ++ni)
#pragma unroll
            for (int r = 0; r < 4; ++r) {
                int fh = mt * 64 + mi * 16 + quad * 4 + r;
                int wk = ni * 16 + l15;
                relW[(size_t)(fh >> 6) * T * 64 + (size_t)((fh & 63) * 64 + wq) * 64 + wk] =
                    acc[mi][ni][r] * LOG2E;
            }
}

// ---------------------------------------------------------------- flash attention, 32x32 MFMA
// block = 128 q-rows (2 image rows), 4 waves, wave owns 32 q x 64-key tiles.
// K/V tiles staged (XOR-swizzled, double-buffered); P transposed via LDS (stride 72).
__global__ __launch_bounds__(256, 2) void attn_kernel(
    const u16* __restrict__ Q, const u16* __restrict__ K, const u16* __restrict__ Vt,
    const float* __restrict__ relH, const float* __restrict__ relW,
    u16* __restrict__ AO) {
    __shared__ __align__(16) u16 kbuf[2][64 * 64];
    __shared__ __align__(16) u16 vbuf[2][64 * 64];
    __shared__ __align__(16) u16 pls[4][32 * 72];
    const int bx = blockIdx.x, h = blockIdx.y;
    const int t0 = bx * 128;
    const int tid = threadIdx.x, wave = tid >> 6, lane = tid & 63;
    const int l31 = lane & 31, h2 = lane >> 5;
    const int hq = 2 * bx + (wave >> 1);
    const int wqband = (wave & 1) * 32;
    const int tw0 = t0 + wave * 32;          // wave's first q row
    const float C1 = 0.18033688011112042f;   // 0.125 * log2(e)

    const u16* Kbase = K + (size_t)h * T * HD;
    const u16* Vbase = Vt + (size_t)h * HD * T;

    // staging geometry (512 chunks of 16B per tile; 2 chunks per thread)
    const int p0 = wave * 64 + lane, p1 = p0 + 256;
    const int sr0 = p0 >> 3, sc0 = (p0 & 7) ^ (sr0 & 7);
    const int sr1 = p1 >> 3, sc1 = (p1 & 7) ^ (sr1 & 7);

    // Q A-fragments in registers: qa[ks] covers k = ks*16 + h2*8 + 0..7
    bf16x8 qa[4];
#pragma unroll
    for (int ks = 0; ks < 4; ++ks)
        qa[ks] = *(const bf16x8*)(Q + (size_t)h * T * HD +
                                  (size_t)(tw0 + l31) * HD + ks * 16 + h2 * 8);
    // rel_w (pre-scaled) for this lane's C-layout slots; rows rr+8g+4*h2
    float rw2[2][16];
#pragma unroll
    for (int kg = 0; kg < 2; ++kg)
#pragma unroll
        for (int g = 0; g < 4; ++g)
#pragma unroll
            for (int rr = 0; rr < 4; ++rr) {
                int t = tw0 + rr + 8 * g + 4 * h2;
                rw2[kg][g * 4 + rr] =
                    relW[((size_t)h * T + t) * 64 + kg * 32 + l31];
            }
    bf16x8 ones;
#pragma unroll
    for (int j = 0; j < 8; ++j) ones[j] = (__bf16)1.0f;

    f32x16 oa[2] = {};
    f32x16 lacc = {};

    // prologue: stage tile 0 into buffer 0
    load_lds16(Kbase + sr0 * HD + sc0 * 8, &kbuf[0][wave * 512]);
    load_lds16(Kbase + sr1 * HD + sc1 * 8, &kbuf[0][2048 + wave * 512]);
    load_lds16(Vbase + (size_t)sr0 * T + sc0 * 8, &vbuf[0][wave * 512]);
    load_lds16(Vbase + (size_t)sr1 * T + sc1 * 8, &vbuf[0][2048 + wave * 512]);

    const float* relHh = relH + ((size_t)(h * 64 + hq) * 64) * 64 + wqband;

    for (int hk = 0; hk < 64; ++hk) {
        const int cur = hk & 1;
        __syncthreads();
        if (hk < 63) {
            const int tk0 = (hk + 1) * 64;
            load_lds16(Kbase + (size_t)(tk0 + sr0) * HD + sc0 * 8, &kbuf[cur ^ 1][wave * 512]);
            load_lds16(Kbase + (size_t)(tk0 + sr1) * HD + sc1 * 8, &kbuf[cur ^ 1][2048 + wave * 512]);
            load_lds16(Vbase + (size_t)sr0 * T + tk0 + sc0 * 8, &vbuf[cur ^ 1][wave * 512]);
            load_lds16(Vbase + (size_t)sr1 * T + tk0 + sc1 * 8, &vbuf[cur ^ 1][2048 + wave * 512]);
        }
        // rel_h bias: 4 float4 loads (rows rr=0..3 per group g)
        float4 rh4[4];
#pragma unroll
        for (int g = 0; g < 4; ++g)
            rh4[g] = *(const float4*)(relHh + (size_t)hk * 64 + 8 * g + 4 * h2);

        const u16* kc = kbuf[cur];
        const u16* vc = vbuf[cur];
        // S = Q K^T : two 32x32 tiles (key groups), 4 k-steps each
        f32x16 s4[2] = {};
#pragma unroll
        for (int kg = 0; kg < 2; ++kg)
#pragma unroll
            for (int ks = 0; ks < 4; ++ks) {
                int key = kg * 32 + l31;
                int ph = (ks * 2 + h2) ^ (key & 7);
                bf16x8 b = *(const bf16x8*)&kc[key * 64 + ph * 8];
                s4[kg] = __builtin_amdgcn_mfma_f32_32x32x16_bf16(qa[ks], b, s4[kg], 0, 0, 0);
            }
        // P = exp2(S*C1 + rel_h + rel_w), write transposed into pls (bf16)
        u16* plw = (u16*)&pls[wave][0];
#pragma unroll
        for (int kg = 0; kg < 2; ++kg)
#pragma unroll
            for (int g = 0; g < 4; ++g)
#pragma unroll
                for (int rr = 0; rr < 4; ++rr) {
                    int reg = g * 4 + rr;
                    float e = exp2_hw(s4[kg][reg] * C1 + rh4[g][rr + 0 == 0 ? rr : rr] + rw2[kg][reg]);
                    plw[(rr + 8 * g + 4 * h2) * 72 + kg * 32 + l31] = f2bf(e);
                }
        asm volatile("s_waitcnt lgkmcnt(0)" ::: "memory");
        // P A-fragments (rows q = l31, k = kst*16 + h2*8 + 0..7)
        bf16x8 paf[4];
#pragma unroll
        for (int kst = 0; kst < 4; ++kst)
            paf[kst] = *(const bf16x8*)&plw[l31 * 72 + kst * 16 + h2 * 8];
#pragma unroll
        for (int kst = 0; kst < 4; ++kst)
            lacc = __builtin_amdgcn_mfma_f32_32x32x16_bf16(paf[kst], ones, lacc, 0, 0, 0);
#pragma unroll
        for (int dg = 0; dg < 2; ++dg)
#pragma unroll
            for (int kst = 0; kst < 4; ++kst) {
                int d = dg * 32 + l31;
                int ph = (kst * 2 + h2) ^ (d & 7);
                bf16x8 vb = *(const bf16x8*)&vc[d * 64 + ph * 8];
                oa[dg] = __builtin_amdgcn_mfma_f32_32x32x16_bf16(paf[kst], vb, oa[dg], 0, 0, 0);
            }
    }
    float inv[16];
#pragma unroll
    for (int r = 0; r < 16; ++r) inv[r] = 1.0f / lacc[r];
#pragma unroll
    for (int dg = 0; dg < 2; ++dg)
#pragma unroll
        for (int g = 0; g < 4; ++g)
#pragma unroll
            for (int rr = 0; rr < 4; ++rr) {
                int reg = g * 4 + rr;
                int t = tw0 + rr + 8 * g + 4 * h2;
                int col = h * HD + dg * 32 + l31;
                AO[(size_t)t * C + col] = f2bf(oa[dg][reg] * inv[reg]);
            }
}

// ---------------------------------------------------------------- launch
extern "C" void kernel_launch(void* const* d_in, const int* in_sizes, int n_in,
                              void* d_out, int out_size, void* d_ws, size_t ws_size,
                              hipStream_t stream) {
    (void)in_sizes; (void)n_in; (void)out_size; (void)ws_size;
    const float* hs  = (const float*)d_in[0];
    const float* q_w = (const float*)d_in[1];
    const float* q_b = (const float*)d_in[2];
    const float* k_w = (const float*)d_in[3];
    const float* k_b = (const float*)d_in[4];
    const float* v_w = (const float*)d_in[5];
    const float* v_b = (const float*)d_in[6];
    const float* p_w = (const float*)d_in[7];
    const float* p_b = (const float*)d_in[8];
    const float* rph = (const float*)d_in[9];
    const float* rpw = (const float*)d_in[10];

    char* ws = (char*)d_ws;
    size_t off = 0;
    auto alloc = [&](size_t bytes) {
        void* p = ws + off;
        off = (off + bytes + 255) & ~(size_t)255;
        return p;
    };
    u16* xb   = (u16*)alloc((size_t)T * C * 2);
    u16* wqb  = (u16*)alloc((size_t)C * C * 2);
    u16* wkb  = (u16*)alloc((size_t)C * C * 2);
    u16* wvb  = (u16*)alloc((size_t)C * C * 2);
    u16* wpb  = (u16*)alloc((size_t)C * C * 2);
    u16* rphb = (u16*)alloc((size_t)127 * HD * 2);
    u16* rpwb = (u16*)alloc((size_t)127 * HD * 2);
    u16* Qb   = (u16*)alloc((size_t)NH * T * HD * 2);
    u16* Kb   = (u16*)alloc((size_t)NH * T * HD * 2);
    u16* Vb   = (u16*)alloc((size_t)NH * T * HD * 2);
    u16* Vt   = (u16*)alloc((size_t)NH * T * HD * 2);
    float* relH = (float*)alloc((size_t)NH * T * 64 * 4);
    float* relW = (float*)alloc((size_t)NH * T * 64 * 4);
    u16* AO   = (u16*)alloc((size_t)T * C * 2);

    const int nmain = (T * C + 4 * C * C) / 4 / 256;
    cvt_main<<<dim3(nmain), dim3(256), 0, stream>>>(hs, q_w, k_w, v_w, p_w,
                                                    xb, wqb, wkb, wvb, wpb);
    cvt_rel<<<dim3(16), dim3(256), 0, stream>>>(rph, rpw, rphb, rpwb);

    gemm_qkv_kernel<<<dim3(32, 6, 3), dim3(256), 0, stream>>>(
        xb, wqb, wkb, wvb, q_b, k_b, v_b, Qb, Kb, Vb);
    vtrans_kernel<<<dim3(64, NH), dim3(256), 0, stream>>>(Vb, Vt);
    relh_kernel<<<dim3(64, NH), dim3(64), 0, stream>>>(Qb, rphb, relH);
    relw_kernel<<<dim3(64, NH), dim3(64), 0, stream>>>(Qb, rpwb, relW);
    attn_kernel<<<dim3(32, NH), dim3(256), 0, stream>>>(Qb, Kb, Vt, relH, relW, AO);
    gemm_proj_kernel<<<dim3(32, 6), dim3(256), 0, stream>>>(AO, wpb, p_b, (float*)d_out);
}

// Round 7
// 241.658 us; speedup vs baseline: 1.5262x; 1.5262x over previous
//
#include <hip/hip_runtime.h>
#include <cstdint>
#include <cstddef>

#define T 4096
#define C 768
#define HD 64
#define NH 12

typedef float f32x4 __attribute__((ext_vector_type(4)));
typedef __bf16 bf16x8 __attribute__((ext_vector_type(8)));
typedef short s16x4 __attribute__((ext_vector_type(4)));
typedef unsigned short u16;

static __device__ __forceinline__ u16 f2bf(float f) {
    union { __bf16 h; u16 u; } cv;
    cv.h = (__bf16)f;
    return cv.u;
}

static __device__ __forceinline__ float exp2_hw(float x) {
    float r;
    asm("v_exp_f32 %0, %1" : "=v"(r) : "v"(x));
    return r;
}

static __device__ __forceinline__ void load_lds16(const void* g, void* l) {
    __builtin_amdgcn_global_load_lds(
        (const __attribute__((address_space(1))) void*)g,
        (__attribute__((address_space(3))) void*)l, 16, 0, 0);
}

// D = A(16x16) * B(16x16) + D, bf16 K=16; A/B: 4 bf16/lane, k = quad*4 + j.
// NOTE: guard on __HIP_DEVICE_COMPILE__ — amdgcn builtins don't exist in the
// host pass (R6's #error fired on host). Asm fallback carries hazard nops
// (R5's NaN: VALU-written pB read by un-padded raw v_mfma).
static __device__ __forceinline__ void mfma16(f32x4& acc, s16x4 a, s16x4 b) {
#if defined(__HIP_DEVICE_COMPILE__)
#if __has_builtin(__builtin_amdgcn_mfma_f32_16x16x16bf16_1k)
    acc = __builtin_amdgcn_mfma_f32_16x16x16bf16_1k(a, b, acc, 0, 0, 0);
#else
    asm volatile("s_nop 2\n\t"
                 "v_mfma_f32_16x16x16_bf16 %0, %1, %2, %0\n\t"
                 "s_nop 7\n\t"
                 "s_nop 7"
                 : "+v"(acc) : "v"(a), "v"(b));
#endif
#else
    (void)acc; (void)a; (void)b;
#endif
}

// ---------------------------------------------------------------- converts
__global__ __launch_bounds__(256) void cvt_main(
    const float* __restrict__ hs, const float* __restrict__ w0,
    const float* __restrict__ w1, const float* __restrict__ w2,
    const float* __restrict__ w3,
    u16* __restrict__ dhs, u16* __restrict__ dw0, u16* __restrict__ dw1,
    u16* __restrict__ dw2, u16* __restrict__ dw3) {
    const int NHS = T * C;
    const int NW = C * C;
    int i = (blockIdx.x * 256 + threadIdx.x) * 4;
    const float* s; u16* d; int j;
    if (i < NHS) { s = hs; d = dhs; j = i; }
    else {
        j = i - NHS;
        int t = j / NW; j -= t * NW;
        s = (t == 0) ? w0 : (t == 1) ? w1 : (t == 2) ? w2 : w3;
        d = (t == 0) ? dw0 : (t == 1) ? dw1 : (t == 2) ? dw2 : dw3;
    }
    float4 v = *(const float4*)(s + j);
    d[j + 0] = f2bf(v.x);
    d[j + 1] = f2bf(v.y);
    d[j + 2] = f2bf(v.z);
    d[j + 3] = f2bf(v.w);
}

__global__ __launch_bounds__(256) void cvt_rel(const float* __restrict__ rh,
                                               const float* __restrict__ rw,
                                               u16* __restrict__ drh,
                                               u16* __restrict__ drw) {
    const int N = 127 * HD;
    int i = (blockIdx.x * 256 + threadIdx.x) * 4;
    if (i >= 2 * N) return;
    const float* s = (i < N) ? rh : rw;
    u16* d = (i < N) ? drh : drw;
    int j = (i < N) ? i : i - N;
    float4 v = *(const float4*)(s + j);
    d[j + 0] = f2bf(v.x);
    d[j + 1] = f2bf(v.y);
    d[j + 2] = f2bf(v.z);
    d[j + 3] = f2bf(v.w);
}

// ---------------------------------------------------------------- QKV GEMM
// 128x128 tile, BK=64, global_load_lds staging with XOR-swizzled LDS
// (16B chunk: phys = logical ^ (row&7)), double-buffered.
__global__ __launch_bounds__(256, 2) void gemm_qkv_kernel(
    const u16* __restrict__ xb,
    const u16* __restrict__ wq, const u16* __restrict__ wk, const u16* __restrict__ wv,
    const float* __restrict__ qb, const float* __restrict__ kb, const float* __restrict__ vb,
    u16* __restrict__ Q, u16* __restrict__ K, u16* __restrict__ V) {
    __shared__ __align__(16) u16 As[2][128 * 64];
    __shared__ __align__(16) u16 Bs[2][128 * 64];
    const int z = blockIdx.z;
    const u16* W = (z == 0) ? wq : (z == 1) ? wk : wv;
    const float* bias = (z == 0) ? qb : (z == 1) ? kb : vb;
    u16* dst = (z == 0) ? Q : (z == 1) ? K : V;
    const int m0 = blockIdx.x * 128, n0 = blockIdx.y * 128;
    const int tid = threadIdx.x;
    const int wave = tid >> 6, lane = tid & 63, quad = lane >> 4, l15 = lane & 15;
    const int r0 = (wave >> 1) * 64, c0 = (wave & 1) * 64;
    int srow[4], sx[4], sdst[4];
#pragma unroll
    for (int i = 0; i < 4; ++i) {
        int p = i * 256 + wave * 64 + lane;
        srow[i] = p >> 3;
        sx[i] = (p & 7) ^ (srow[i] & 7);
        sdst[i] = (i * 256 + wave * 64) * 8;
    }
    f32x4 acc[4][4] = {};
#pragma unroll
    for (int i = 0; i < 4; ++i) {
        load_lds16(xb + (size_t)(m0 + srow[i]) * C + sx[i] * 8, &As[0][sdst[i]]);
        load_lds16(W + (size_t)(n0 + srow[i]) * C + sx[i] * 8, &Bs[0][sdst[i]]);
    }
    for (int kt = 0; kt < 12; ++kt) {
        const int cur = kt & 1;
        __syncthreads();
        if (kt < 11) {
            const int k0 = (kt + 1) * 64;
#pragma unroll
            for (int i = 0; i < 4; ++i) {
                load_lds16(xb + (size_t)(m0 + srow[i]) * C + k0 + sx[i] * 8, &As[cur ^ 1][sdst[i]]);
                load_lds16(W + (size_t)(n0 + srow[i]) * C + k0 + sx[i] * 8, &Bs[cur ^ 1][sdst[i]]);
            }
        }
#pragma unroll
        for (int kk = 0; kk < 2; ++kk) {
            bf16x8 af[4], bfr[4];
#pragma unroll
            for (int mi = 0; mi < 4; ++mi) {
                int r = r0 + mi * 16 + l15;
                af[mi] = *(const bf16x8*)&As[cur][r * 64 + (((kk * 4 + quad) ^ (r & 7)) * 8)];
            }
#pragma unroll
            for (int ni = 0; ni < 4; ++ni) {
                int r = c0 + ni * 16 + l15;
                bfr[ni] = *(const bf16x8*)&Bs[cur][r * 64 + (((kk * 4 + quad) ^ (r & 7)) * 8)];
            }
#pragma unroll
            for (int mi = 0; mi < 4; ++mi)
#pragma unroll
                for (int ni = 0; ni < 4; ++ni)
                    acc[mi][ni] = __builtin_amdgcn_mfma_f32_16x16x32_bf16(af[mi], bfr[ni], acc[mi][ni], 0, 0, 0);
        }
    }
#pragma unroll
    for (int mi = 0; mi < 4; ++mi)
#pragma unroll
        for (int ni = 0; ni < 4; ++ni)
#pragma unroll
            for (int r = 0; r < 4; ++r) {
                int m = m0 + r0 + mi * 16 + quad * 4 + r;
                int n = n0 + c0 + ni * 16 + l15;
                float v = acc[mi][ni][r] + bias[n];
                dst[(size_t)(n >> 6) * T * HD + (size_t)m * HD + (n & 63)] = f2bf(v);
            }
}

// ---------------------------------------------------------------- proj GEMM (fp32 out)
__global__ __launch_bounds__(256, 2) void gemm_proj_kernel(
    const u16* __restrict__ A, const u16* __restrict__ W,
    const float* __restrict__ bias, float* __restrict__ out) {
    __shared__ __align__(16) u16 As[2][128 * 64];
    __shared__ __align__(16) u16 Bs[2][128 * 64];
    const int m0 = blockIdx.x * 128, n0 = blockIdx.y * 128;
    const int tid = threadIdx.x;
    const int wave = tid >> 6, lane = tid & 63, quad = lane >> 4, l15 = lane & 15;
    const int r0 = (wave >> 1) * 64, c0 = (wave & 1) * 64;
    int srow[4], sx[4], sdst[4];
#pragma unroll
    for (int i = 0; i < 4; ++i) {
        int p = i * 256 + wave * 64 + lane;
        srow[i] = p >> 3;
        sx[i] = (p & 7) ^ (srow[i] & 7);
        sdst[i] = (i * 256 + wave * 64) * 8;
    }
    f32x4 acc[4][4] = {};
#pragma unroll
    for (int i = 0; i < 4; ++i) {
        load_lds16(A + (size_t)(m0 + srow[i]) * C + sx[i] * 8, &As[0][sdst[i]]);
        load_lds16(W + (size_t)(n0 + srow[i]) * C + sx[i] * 8, &Bs[0][sdst[i]]);
    }
    for (int kt = 0; kt < 12; ++kt) {
        const int cur = kt & 1;
        __syncthreads();
        if (kt < 11) {
            const int k0 = (kt + 1) * 64;
#pragma unroll
            for (int i = 0; i < 4; ++i) {
                load_lds16(A + (size_t)(m0 + srow[i]) * C + k0 + sx[i] * 8, &As[cur ^ 1][sdst[i]]);
                load_lds16(W + (size_t)(n0 + srow[i]) * C + k0 + sx[i] * 8, &Bs[cur ^ 1][sdst[i]]);
            }
        }
#pragma unroll
        for (int kk = 0; kk < 2; ++kk) {
            bf16x8 af[4], bfr[4];
#pragma unroll
            for (int mi = 0; mi < 4; ++mi) {
                int r = r0 + mi * 16 + l15;
                af[mi] = *(const bf16x8*)&As[cur][r * 64 + (((kk * 4 + quad) ^ (r & 7)) * 8)];
            }
#pragma unroll
            for (int ni = 0; ni < 4; ++ni) {
                int r = c0 + ni * 16 + l15;
                bfr[ni] = *(const bf16x8*)&Bs[cur][r * 64 + (((kk * 4 + quad) ^ (r & 7)) * 8)];
            }
#pragma unroll
            for (int mi = 0; mi < 4; ++mi)
#pragma unroll
                for (int ni = 0; ni < 4; ++ni)
                    acc[mi][ni] = __builtin_amdgcn_mfma_f32_16x16x32_bf16(af[mi], bfr[ni], acc[mi][ni], 0, 0, 0);
        }
    }
#pragma unroll
    for (int mi = 0; mi < 4; ++mi)
#pragma unroll
        for (int ni = 0; ni < 4; ++ni)
#pragma unroll
            for (int r = 0; r < 4; ++r) {
                int m = m0 + r0 + mi * 16 + quad * 4 + r;
                int n = n0 + c0 + ni * 16 + l15;
                out[(size_t)m * C + n] = acc[mi][ni][r] + bias[n];
            }
}

// ---------------------------------------------------------------- V transpose
__global__ __launch_bounds__(256) void vtrans_kernel(const u16* __restrict__ V,
                                                     u16* __restrict__ Vt) {
    __shared__ __align__(16) u16 tl[64 * 72];
    const int h = blockIdx.y, t0 = blockIdx.x * 64, tid = threadIdx.x;
#pragma unroll
    for (int i = 0; i < 2; ++i) {
        int c = i * 256 + tid;
        int row = c >> 3, col = (c & 7) * 8;
        union { float4 f; u16 u[8]; } cv;
        cv.f = *(const float4*)(V + (size_t)h * T * HD + (size_t)(t0 + row) * HD + col);
#pragma unroll
        for (int j = 0; j < 8; ++j) tl[(col + j) * 72 + row] = cv.u[j];
    }
    __syncthreads();
#pragma unroll
    for (int i = 0; i < 2; ++i) {
        int c = i * 256 + tid;
        int drow = c >> 3, tcol = (c & 7) * 8;
        float4 v = *(const float4*)&tl[drow * 72 + tcol];
        *(float4*)(Vt + (size_t)(h * HD + drow) * T + t0 + tcol) = v;
    }
}

// ---------------------------------------------------------------- rel_h
// OUT: relH[h][hq][wq][hk] (hk contiguous), pre-scaled by log2e.
// grid (64 hq, NH), 4 waves; wave w: hk-group w*16. D[hk][wq] = Rh' . Q^T.
__global__ __launch_bounds__(256) void relh_kernel(const u16* __restrict__ Q,
                                                   const u16* __restrict__ rph,
                                                   float* __restrict__ relH) {
    const float LOG2E = 1.4426950408889634f;
    const int hq = blockIdx.x, h = blockIdx.y;
    const int tid = threadIdx.x, wave = tid >> 6, lane = tid & 63;
    const int quad = lane >> 4, l15 = lane & 15;
    f32x4 acc[4] = {};
    bf16x8 a[2], b[4][2];
#pragma unroll
    for (int kk = 0; kk < 2; ++kk) {
        int hk = wave * 16 + l15;                      // A: m = hk
        a[kk] = *(const bf16x8*)(rph + (size_t)(hq - hk + 63) * HD + kk * 32 + quad * 8);
    }
#pragma unroll
    for (int nt = 0; nt < 4; ++nt)
#pragma unroll
        for (int kk = 0; kk < 2; ++kk)                 // B: n = wq
            b[nt][kk] = *(const bf16x8*)(Q + (size_t)h * T * HD +
                                         (size_t)(hq * 64 + nt * 16 + l15) * HD + kk * 32 + quad * 8);
#pragma unroll
    for (int nt = 0; nt < 4; ++nt) {
        acc[nt] = __builtin_amdgcn_mfma_f32_16x16x32_bf16(a[0], b[nt][0], acc[nt], 0, 0, 0);
        acc[nt] = __builtin_amdgcn_mfma_f32_16x16x32_bf16(a[1], b[nt][1], acc[nt], 0, 0, 0);
    }
#pragma unroll
    for (int nt = 0; nt < 4; ++nt) {
        float4 v;
        v.x = acc[nt][0] * LOG2E; v.y = acc[nt][1] * LOG2E;
        v.z = acc[nt][2] * LOG2E; v.w = acc[nt][3] * LOG2E;
        *(float4*)(relH + (((size_t)(h * 64 + hq) * 64 + nt * 16 + l15) * 64) +
                   wave * 16 + quad * 4) = v;
    }
}

// ---------------------------------------------------------------- rel_w
// OUT: relW[h][t][wk] (wk contiguous), pre-scaled by log2e.
// grid (64 wq, NH), 4 waves; wave w: hq-group w*16. D[hq][wk] = Q . Rw'^T.
__global__ __launch_bounds__(256) void relw_kernel(const u16* __restrict__ Q,
                                                   const u16* __restrict__ rpw,
                                                   float* __restrict__ relW) {
    const float LOG2E = 1.4426950408889634f;
    const int wq = blockIdx.x, h = blockIdx.y;
    const int tid = threadIdx.x, wave = tid >> 6, lane = tid & 63;
    const int quad = lane >> 4, l15 = lane & 15;
    f32x4 acc[4] = {};
    bf16x8 a[2], b[4][2];
#pragma unroll
    for (int kk = 0; kk < 2; ++kk) {
        int hqr = wave * 16 + l15;                     // A: m = hq
        a[kk] = *(const bf16x8*)(Q + (size_t)h * T * HD +
                                 (size_t)(hqr * 64 + wq) * HD + kk * 32 + quad * 8);
    }
#pragma unroll
    for (int nt = 0; nt < 4; ++nt)
#pragma unroll
        for (int kk = 0; kk < 2; ++kk) {
            int wk = nt * 16 + l15;                    // B: n = wk
            b[nt][kk] = *(const bf16x8*)(rpw + (size_t)(wq - wk + 63) * HD + kk * 32 + quad * 8);
        }
#pragma unroll
    for (int nt = 0; nt < 4; ++nt) {
        acc[nt] = __builtin_amdgcn_mfma_f32_16x16x32_bf16(a[0], b[nt][0], acc[nt], 0, 0, 0);
        acc[nt] = __builtin_amdgcn_mfma_f32_16x16x32_bf16(a[1], b[nt][1], acc[nt], 0, 0, 0);
    }
#pragma unroll
    for (int nt = 0; nt < 4; ++nt)
#pragma unroll
        for (int r = 0; r < 4; ++r) {
            int hqr = wave * 16 + quad * 4 + r;
            relW[((size_t)h * T + hqr * 64 + wq) * 64 + nt * 16 + l15] = acc[nt][r] * LOG2E;
        }
}

// ---------------------------------------------------------------- flash attention (S^T form)
// block = 64 q (one image row hq); 4 waves x 16 q. S^T = K.Q^T so P^T exits
// MFMA directly in K=16 B-fragment layout -> PV via mfma 16x16x16, no LDS
// round trip. rel_h = scalar/lane/iter (float4 per 4 iters); rel_w in regs.
__global__ __launch_bounds__(256, 3) void attn_kernel(
    const u16* __restrict__ Q, const u16* __restrict__ K, const u16* __restrict__ Vt,
    const float* __restrict__ relH, const float* __restrict__ relW,
    u16* __restrict__ AO) {
    __shared__ __align__(16) u16 kbuf[2][64 * 64];
    __shared__ __align__(16) u16 vbuf[2][64 * 64];
    const int hq = blockIdx.x, h = blockIdx.y;
    const int t0 = hq * 64;
    const int tid = threadIdx.x, wave = tid >> 6, lane = tid & 63;
    const int quad = lane >> 4, l15 = lane & 15;
    const float C1 = 0.18033688011112042f;   // 0.125 * log2(e)

    const u16* Kbase = K + (size_t)h * T * HD;
    const u16* Vbase = Vt + (size_t)h * HD * T;

    // staging geometry (512 x 16B chunks per tile; 2 per thread)
    const int p0 = wave * 128 + lane, p1 = p0 + 64;
    const int sr0 = p0 >> 3, sx0 = (p0 & 7) ^ (sr0 & 7);
    const int sr1 = p1 >> 3, sx1 = (p1 & 7) ^ (sr1 & 7);
    const int lds0 = wave * 1024, lds1 = wave * 1024 + 512;

    // Q B-fragments (n = q = l15, k = kk*32 + quad*8)
    bf16x8 qa[2];
#pragma unroll
    for (int kk = 0; kk < 2; ++kk)
        qa[kk] = *(const bf16x8*)(Q + (size_t)h * T * HD +
                                  (size_t)(t0 + wave * 16 + l15) * HD + kk * 32 + quad * 8);
    // rel_w (pre-scaled): lane's q row, wk = g*16 + quad*4 + r
    const float* rwb = relW + ((size_t)h * T + (t0 + wave * 16 + l15)) * 64;
    float4 rw4[4];
#pragma unroll
    for (int g = 0; g < 4; ++g)
        rw4[g] = *(const float4*)(rwb + g * 16 + quad * 4);
    // rel_h (pre-scaled): lane's q row, consecutive hk
    const float* rhb = relH + ((size_t)(h * 64 + hq) * 64 + wave * 16 + l15) * 64;

    s16x4 ones;
#pragma unroll
    for (int j = 0; j < 4; ++j) ones[j] = (short)0x3F80;

    f32x4 oa[4] = {};
    f32x4 lacc = {};

    // prologue: stage tile 0
    load_lds16(Kbase + sr0 * HD + sx0 * 8, &kbuf[0][lds0]);
    load_lds16(Kbase + sr1 * HD + sx1 * 8, &kbuf[0][lds1]);
    load_lds16(Vbase + (size_t)sr0 * T + sx0 * 8, &vbuf[0][lds0]);
    load_lds16(Vbase + (size_t)sr1 * T + sx1 * 8, &vbuf[0][lds1]);

    for (int hk4 = 0; hk4 < 16; ++hk4) {
        float4 rh4 = *(const float4*)(rhb + hk4 * 4);
#pragma unroll
        for (int rr = 0; rr < 4; ++rr) {
            const int hk = hk4 * 4 + rr;
            const int cur = rr & 1;
            __syncthreads();
            if (hk < 63) {
                const int tk0 = (hk + 1) * 64;
                load_lds16(Kbase + (size_t)(tk0 + sr0) * HD + sx0 * 8, &kbuf[cur ^ 1][lds0]);
                load_lds16(Kbase + (size_t)(tk0 + sr1) * HD + sx1 * 8, &kbuf[cur ^ 1][lds1]);
                load_lds16(Vbase + (size_t)sr0 * T + tk0 + sx0 * 8, &vbuf[cur ^ 1][lds0]);
                load_lds16(Vbase + (size_t)sr1 * T + tk0 + sx1 * 8, &vbuf[cur ^ 1][lds1]);
            }
            const u16* kc = kbuf[cur];
            const u16* vc = vbuf[cur];
            // S^T = K . Q^T : A = K rows (m = key), B = qa
            f32x4 s4[4] = {};
#pragma unroll
            for (int g = 0; g < 4; ++g)
#pragma unroll
                for (int kk = 0; kk < 2; ++kk) {
                    bf16x8 af = *(const bf16x8*)&kc[g * 1024 + l15 * 64 +
                                                    (((kk * 4 + quad) ^ (l15 & 7)) * 8)];
                    s4[g] = __builtin_amdgcn_mfma_f32_16x16x32_bf16(af, qa[kk], s4[g], 0, 0, 0);
                }
            // P^T = exp2(S^T*C1 + rel_h + rel_w), packed directly as K=16 B-frags
            const float rhc = (rr == 0) ? rh4.x : (rr == 1) ? rh4.y : (rr == 2) ? rh4.z : rh4.w;
            s16x4 pB[4];
#pragma unroll
            for (int g = 0; g < 4; ++g) {
#pragma unroll
                for (int r = 0; r < 4; ++r) {
                    float e = exp2_hw(s4[g][r] * C1 + (rhc + rw4[g][r]));
                    pB[g][r] = (short)f2bf(e);
                }
            }
            // O^T += V^T . P^T ; rowsum += 1 . P^T
#pragma unroll
            for (int g = 0; g < 4; ++g) {
                mfma16(lacc, ones, pB[g]);
#pragma unroll
                for (int dg = 0; dg < 4; ++dg) {
                    s16x4 vf = *(const s16x4*)&vc[dg * 1024 + l15 * 64 +
                                                  (((2 * g + (quad >> 1)) ^ (l15 & 7)) * 8) +
                                                  (quad & 1) * 4];
                    mfma16(oa[dg], vf, pB[g]);
                }
            }
        }
    }
    const float inv = 1.0f / lacc[0];
    const size_t trow = (size_t)(t0 + wave * 16 + l15) * C + h * HD;
#pragma unroll
    for (int dg = 0; dg < 4; ++dg) {
        unsigned int lo = (unsigned int)f2bf(oa[dg][0] * inv) |
                          ((unsigned int)f2bf(oa[dg][1] * inv) << 16);
        unsigned int hi = (unsigned int)f2bf(oa[dg][2] * inv) |
                          ((unsigned int)f2bf(oa[dg][3] * inv) << 16);
        uint2 st; st.x = lo; st.y = hi;
        *(uint2*)(AO + trow + dg * 16 + quad * 4) = st;
    }
}

// ---------------------------------------------------------------- launch
extern "C" void kernel_launch(void* const* d_in, const int* in_sizes, int n_in,
                              void* d_out, int out_size, void* d_ws, size_t ws_size,
                              hipStream_t stream) {
    (void)in_sizes; (void)n_in; (void)out_size; (void)ws_size;
    const float* hs  = (const float*)d_in[0];
    const float* q_w = (const float*)d_in[1];
    const float* q_b = (const float*)d_in[2];
    const float* k_w = (const float*)d_in[3];
    const float* k_b = (const float*)d_in[4];
    const float* v_w = (const float*)d_in[5];
    const float* v_b = (const float*)d_in[6];
    const float* p_w = (const float*)d_in[7];
    const float* p_b = (const float*)d_in[8];
    const float* rph = (const float*)d_in[9];
    const float* rpw = (const float*)d_in[10];

    char* ws = (char*)d_ws;
    size_t off = 0;
    auto alloc = [&](size_t bytes) {
        void* p = ws + off;
        off = (off + bytes + 255) & ~(size_t)255;
        return p;
    };
    u16* xb   = (u16*)alloc((size_t)T * C * 2);
    u16* wqb  = (u16*)alloc((size_t)C * C * 2);
    u16* wkb  = (u16*)alloc((size_t)C * C * 2);
    u16* wvb  = (u16*)alloc((size_t)C * C * 2);
    u16* wpb  = (u16*)alloc((size_t)C * C * 2);
    u16* rphb = (u16*)alloc((size_t)127 * HD * 2);
    u16* rpwb = (u16*)alloc((size_t)127 * HD * 2);
    u16* Qb   = (u16*)alloc((size_t)NH * T * HD * 2);
    u16* Kb   = (u16*)alloc((size_t)NH * T * HD * 2);
    u16* Vb   = (u16*)alloc((size_t)NH * T * HD * 2);
    u16* Vt   = (u16*)alloc((size_t)NH * T * HD * 2);
    float* relH = (float*)alloc((size_t)NH * T * 64 * 4);
    float* relW = (float*)alloc((size_t)NH * T * 64 * 4);
    u16* AO   = (u16*)alloc((size_t)T * C * 2);

    const int nmain = (T * C + 4 * C * C) / 4 / 256;
    cvt_main<<<dim3(nmain), dim3(256), 0, stream>>>(hs, q_w, k_w, v_w, p_w,
                                                    xb, wqb, wkb, wvb, wpb);
    cvt_rel<<<dim3(16), dim3(256), 0, stream>>>(rph, rpw, rphb, rpwb);

    gemm_qkv_kernel<<<dim3(32, 6, 3), dim3(256), 0, stream>>>(
        xb, wqb, wkb, wvb, q_b, k_b, v_b, Qb, Kb, Vb);
    vtrans_kernel<<<dim3(64, NH), dim3(256), 0, stream>>>(Vb, Vt);
    relh_kernel<<<dim3(64, NH), dim3(256), 0, stream>>>(Qb, rphb, relH);
    relw_kernel<<<dim3(64, NH), dim3(256), 0, stream>>>(Qb, rpwb, relW);
    attn_kernel<<<dim3(64, NH), dim3(256), 0, stream>>>(Qb, Kb, Vt, relH, relW, AO);
    gemm_proj_kernel<<<dim3(32, 6), dim3(256), 0, stream>>>(AO, wpb, p_b, (float*)d_out);
}